// Round 17
// baseline (96.403 us; speedup 1.0000x reference)
//
#include <hip/hip_runtime.h>
#include <stdint.h>

#define NE 256      // experts
#define TK 8        // top-k experts
#define TPB 64      // tokens per block (256 threads = 4 waves; 16 tokens/wave)
#define CDW 76      // dwords per token row: 36 u64 slots (32 cand + 4 pad) + cnt; 304B
#define CNT_OFF 72

typedef float pf2 __attribute__((ext_vector_type(2)));

// ---------- packed f32 VOP3P helpers (bit-identical IEEE) ----------
__device__ __forceinline__ pf2 pk_fma_ss(pf2 a, pf2 b, pf2 cs) {
    pf2 d; asm("v_pk_fma_f32 %0, %1, %2, %3" : "=v"(d) : "v"(a), "v"(b), "s"(cs)); return d;
}
__device__ __forceinline__ pf2 pk_fma_sv(pf2 as, pf2 b, pf2 c) {
    pf2 d; asm("v_pk_fma_f32 %0, %1, %2, %3" : "=v"(d) : "s"(as), "v"(b), "v"(c)); return d;
}
__device__ __forceinline__ pf2 pk_fma_vv(pf2 a, pf2 b, pf2 c) {
    pf2 d; asm("v_pk_fma_f32 %0, %1, %2, %3" : "=v"(d) : "v"(a), "v"(b), "v"(c)); return d;
}
__device__ __forceinline__ pf2 pk_mul_s(pf2 a, pf2 bs) {
    pf2 d; asm("v_pk_mul_f32 %0, %1, %2" : "=v"(d) : "v"(a), "s"(bs)); return d;
}
__device__ __forceinline__ pf2 pk_mul_v(pf2 a, pf2 b) {
    pf2 d; asm("v_pk_mul_f32 %0, %1, %2" : "=v"(d) : "v"(a), "v"(b)); return d;
}
__device__ __forceinline__ pf2 pk_add_s(pf2 a, pf2 bs) {
    pf2 d; asm("v_pk_add_f32 %0, %1, %2" : "=v"(d) : "v"(a), "s"(bs)); return d;
}

// Bit-exact packed replica of numpy's SIMD float32 exp (Cephes FMA path).
// DO NOT TOUCH — validated bit-exact vs the np reference (rounds 3-16).
__device__ __forceinline__ pf2 np_expf2(pf2 v) {
    const pf2 LOG2E  = {1.44269504088896341f, 1.44269504088896341f};
    const pf2 NLN2HI = {-0.693359375f, -0.693359375f};
    const pf2 LN2LO  = {2.12194440e-4f, 2.12194440e-4f};
    const pf2 A0     = {1.9875691500E-4f, 1.9875691500E-4f};
    const pf2 A1     = {1.3981999507E-3f, 1.3981999507E-3f};
    const pf2 A2     = {8.3334519073E-3f, 8.3334519073E-3f};
    const pf2 A3     = {4.1665795894E-2f, 4.1665795894E-2f};
    const pf2 A4     = {1.6666665459E-1f, 1.6666665459E-1f};
    const pf2 A5     = {5.0000001201E-1f, 5.0000001201E-1f};
    const pf2 ONE    = {1.0f, 1.0f};

    pf2 m = pk_mul_s(v, LOG2E);
    pf2 q; q.x = rintf(m.x); q.y = rintf(m.y);
    pf2 t = pk_fma_sv(NLN2HI, q, v);
    t = pk_fma_sv(LN2LO, q, t);
    pf2 t2 = pk_mul_v(t, t);
    pf2 p = pk_fma_sv(A0, t, A1);
    p = pk_fma_ss(p, t, A2);
    p = pk_fma_ss(p, t, A3);
    p = pk_fma_ss(p, t, A4);
    p = pk_fma_ss(p, t, A5);
    p = pk_fma_vv(p, t2, t);
    p = pk_add_s(p, ONE);
    pf2 r;
    r.x = ldexpf(p.x, (int)q.x);
    r.y = ldexpf(p.y, (int)q.y);
    return r;
}

// Correctly-rounded 1/d for d in [1, 2^20] (validated r10-r16).
__device__ __forceinline__ float crdiv1(float d) {
    float y0 = __builtin_amdgcn_rcpf(d);
    float e0 = fmaf(-d, y0, 1.0f);
    float y1 = fmaf(e0, y0, y0);
    float e1 = fmaf(-d, y1, 1.0f);
    float y2 = fmaf(e1, y1, y1);
    float r  = fmaf(-d, y2, 1.0f);
    return fmaf(r, y2, y2);
}

// f32 -> monotone u32 (order-preserving). 0.0f -> 0x80000000.
__device__ __forceinline__ unsigned ordkey(float v) {
    int b = __float_as_int(v);
    return (unsigned)(b ^ ((b >> 31) | 0x80000000));
}
__device__ __forceinline__ float inv_ordkey(unsigned u) {
    unsigned b = (u & 0x80000000u) ? (u ^ 0x80000000u) : ~u;
    return __uint_as_float(b);
}

__device__ __forceinline__ float rlanef(float v, int l) {
    return __int_as_float(__builtin_amdgcn_readlane(__float_as_int(v), l));
}
__device__ __forceinline__ unsigned rlaneu(unsigned v, int l) {
    return (unsigned)__builtin_amdgcn_readlane((int)v, l);
}
__device__ __forceinline__ unsigned rlaneu_s(unsigned v, int l) {   // dynamic lane (SGPR)
    return (unsigned)__builtin_amdgcn_readlane((int)v, l);
}
__device__ __forceinline__ unsigned umax_(unsigned a, unsigned b) { return a > b ? a : b; }
__device__ __forceinline__ int mbcnt64(unsigned long long m) {
    return __builtin_amdgcn_mbcnt_hi((unsigned)(m >> 32),
           __builtin_amdgcn_mbcnt_lo((unsigned)m, 0u));
}

// DPP cross-lane read (pure VALU, no LDS).
template <int CTRL>
__device__ __forceinline__ float dppf(float x) {
    int xi = __float_as_int(x);
    return __int_as_float(__builtin_amdgcn_update_dpp(xi, xi, CTRL, 0xF, 0xF, false));
}
#define DPP_XOR1  0xB1   // quad_perm [1,0,3,2]
#define DPP_XOR2  0x4E   // quad_perm [2,3,0,1]
#define DPP_ROR4  0x124  // row_ror:4
#define DPP_ROR8  0x128  // row_ror:8

// Branchless sorted-descending top-8 insertion (u64 = key<<32 | invidx).
#define INS8(cand) do {                                                \
    const uint64_t c_ = (cand);                                        \
    const bool q0 = c_ > v0, q1 = c_ > v1, q2 = c_ > v2, q3 = c_ > v3; \
    const bool q4 = c_ > v4, q5 = c_ > v5, q6 = c_ > v6, q7 = c_ > v7; \
    v7 = q7 ? (q6 ? v6 : c_) : v7;                                     \
    v6 = q6 ? (q5 ? v5 : c_) : v6;                                     \
    v5 = q5 ? (q4 ? v4 : c_) : v5;                                     \
    v4 = q4 ? (q3 ? v3 : c_) : v4;                                     \
    v3 = q3 ? (q2 ? v2 : c_) : v3;                                     \
    v2 = q2 ? (q1 ? v1 : c_) : v2;                                     \
    v1 = q1 ? (q0 ? v0 : c_) : v1;                                     \
    v0 = q0 ? c_ : v0;                                                 \
} while (0)

// ===== 2-tokens-per-wave phase-1 =====
// Lanes 0-31 -> token A, lanes 32-63 -> token B. Lane l owns experts
// [(l&31)*8, +8) of its token. Group = 4-lane quad (32 experts).
// All selection VALUES bit-identical to r11-r16 (top-2 tree-invariant,
// min exact, same rank predicate, same keys/filter) — only lane layout changed.
__device__ __forceinline__ void score_pair(
    const float4 xa, const float4 xb,
    const pf2 bp0, const pf2 bp1, const pf2 bp2, const pf2 bp3,
    const int lane, const int bpa1,
    uint32_t* rowA, uint32_t* rowB, uint32_t* rowMine)
{
    const int l31 = lane & 31;
    const int h   = lane >> 5;

    const pf2 ONE = {1.0f, 1.0f};
    pf2 eA = np_expf2((pf2){-xa.x, -xa.y});
    pf2 eB = np_expf2((pf2){-xa.z, -xa.w});
    pf2 eC = np_expf2((pf2){-xb.x, -xb.y});
    pf2 eD = np_expf2((pf2){-xb.z, -xb.w});
    pf2 dA = pk_add_s(eA, ONE);
    pf2 dB = pk_add_s(eB, ONE);
    pf2 dC = pk_add_s(eC, ONE);
    pf2 dD = pk_add_s(eD, ONE);
    const float s0 = crdiv1(dA.x), s1 = crdiv1(dA.y);
    const float s2 = crdiv1(dB.x), s3 = crdiv1(dB.y);
    const float s4 = crdiv1(dC.x), s5 = crdiv1(dC.y);
    const float s6 = crdiv1(dD.x), s7 = crdiv1(dD.y);
    const float c0 = s0 + bp0.x, c1 = s1 + bp0.y;
    const float c2 = s2 + bp1.x, c3 = s3 + bp1.y;
    const float c4 = s4 + bp2.x, c5 = s5 + bp2.y;
    const float c6 = s6 + bp3.x, c7 = s7 + bp3.y;

    // local top-2 of my 8 values (tournament; top-2 values tree-invariant)
    float a1 = fmaxf(c0, c1), a2 = fminf(c0, c1);
    float b1 = fmaxf(c2, c3), b2 = fminf(c2, c3);
    float t1 = fmaxf(a1, b1), t2 = fmaxf(fminf(a1, b1), fmaxf(a2, b2));
    float p1 = fmaxf(c4, c5), p2 = fminf(c4, c5);
    float q1 = fmaxf(c6, c7), q2 = fminf(c6, c7);
    float u1 = fmaxf(p1, q1), u2 = fmaxf(fminf(p1, q1), fmaxf(p2, q2));
    float m1 = fmaxf(t1, u1), m2 = fmaxf(fminf(t1, u1), fmaxf(t2, u2));

    // 2-level DPP butterfly across the 4-lane group (= 32 experts)
    {
        float px1 = dppf<DPP_XOR1>(m1), px2 = dppf<DPP_XOR1>(m2);
        float n1 = fmaxf(m1, px1);
        m2 = fmaxf(fminf(m1, px1), fmaxf(m2, px2)); m1 = n1;
    }
    {
        float px1 = dppf<DPP_XOR2>(m1), px2 = dppf<DPP_XOR2>(m2);
        float n1 = fmaxf(m1, px1);
        m2 = fmaxf(fminf(m1, px1), fmaxf(m2, px2)); m1 = n1;
    }
    const float gs = m1 + m2;   // uniform across the group's 4 lanes

    // rank: lane (group a, j=l&3) compares its token's groups b1=j and b2=j+4.
    // Together the group's 4 lanes cover all 8 b's exactly once.
    // term(a,b) = (g_b > g_a) || (g_b == g_a && b < a); tie-masks compile-time.
    const float gb1 = __int_as_float(
        __builtin_amdgcn_ds_bpermute(bpa1,      __float_as_int(gs)));
    const float gb2 = __int_as_float(
        __builtin_amdgcn_ds_bpermute(bpa1 + 64, __float_as_int(gs)));
    const unsigned long long t1m = __ballot(gb1 > gs)
        | (__ballot(gb1 == gs) & 0xFFFF7310FFFF7310ull);   // b=j   < a
    const unsigned long long t2m = __ballot(gb2 > gs)
        | (__ballot(gb2 == gs) & 0x7310000073100000ull);   // b=j+4 < a
    unsigned kmA = 0, kmB = 0;
    #pragma unroll
    for (int a = 0; a < 8; ++a) {
        const int rA = __popcll((t1m >> (4 * a)) & 0xFull)
                     + __popcll((t2m >> (4 * a)) & 0xFull);
        const int rB = __popcll((t1m >> (32 + 4 * a)) & 0xFull)
                     + __popcll((t2m >> (32 + 4 * a)) & 0xFull);
        kmA |= (rA < 4 ? 1u : 0u) << a;
        kmB |= (rB < 4 ? 1u : 0u) << a;
    }
    const unsigned km = h ? kmB : kmA;
    const int ga = l31 >> 2;
    const bool keep = (km >> ga) & 1u;

    // tau0 per token: min over kept groups of m2 (exact, idempotent dup-safe).
    // ror4+ror8 gives the 4-group min within each 16-row; combine row pairs
    // via readlanes (rows 0,1 = token A; rows 2,3 = token B).
    const float inf_ = __uint_as_float(0x7F800000u);
    float mm = keep ? m2 : inf_;
    mm = fminf(mm, dppf<DPP_ROR4>(mm));
    mm = fminf(mm, dppf<DPP_ROR8>(mm));
    const float tA = fminf(rlanef(mm, 0),  rlanef(mm, 16));
    const float tB = fminf(rlanef(mm, 32), rlanef(mm, 48));
    const float t0f = h ? tB : tA;

    // candidate filter
    const bool cd0 = keep && (c0 >= t0f);
    const bool cd1 = keep && (c1 >= t0f);
    const bool cd2 = keep && (c2 >= t0f);
    const bool cd3 = keep && (c3 >= t0f);
    const bool cd4 = keep && (c4 >= t0f);
    const bool cd5 = keep && (c5 >= t0f);
    const bool cd6 = keep && (c6 >= t0f);
    const bool cd7 = keep && (c7 >= t0f);
    const unsigned long long B0 = __ballot(cd0);
    const unsigned long long B1 = __ballot(cd1);
    const unsigned long long B2 = __ballot(cd2);
    const unsigned long long B3 = __ballot(cd3);
    const unsigned long long B4 = __ballot(cd4);
    const unsigned long long B5 = __ballot(cd5);
    const unsigned long long B6 = __ballot(cd6);
    const unsigned long long B7 = __ballot(cd7);

    // per-half cumulative slot offsets (scalar)
    const unsigned pl0 = __popc((unsigned)B0), ph0 = __popc((unsigned)(B0 >> 32));
    const unsigned pl1 = __popc((unsigned)B1), ph1 = __popc((unsigned)(B1 >> 32));
    const unsigned pl2 = __popc((unsigned)B2), ph2 = __popc((unsigned)(B2 >> 32));
    const unsigned pl3 = __popc((unsigned)B3), ph3 = __popc((unsigned)(B3 >> 32));
    const unsigned pl4 = __popc((unsigned)B4), ph4 = __popc((unsigned)(B4 >> 32));
    const unsigned pl5 = __popc((unsigned)B5), ph5 = __popc((unsigned)(B5 >> 32));
    const unsigned pl6 = __popc((unsigned)B6), ph6 = __popc((unsigned)(B6 >> 32));
    const unsigned pl7 = __popc((unsigned)B7), ph7 = __popc((unsigned)(B7 >> 32));
    const unsigned pA0 = 0,        pA1 = pl0,       pA2 = pA1 + pl1, pA3 = pA2 + pl2;
    const unsigned pA4 = pA3 + pl3, pA5 = pA4 + pl4, pA6 = pA5 + pl5, pA7 = pA6 + pl6;
    const unsigned cntA = pA7 + pl7;
    const unsigned pB0 = 0,        pB1 = ph0,       pB2 = pB1 + ph1, pB3 = pB2 + ph2;
    const unsigned pB4 = pB3 + ph3, pB5 = pB4 + ph4, pB6 = pB5 + ph5, pB7 = pB6 + ph6;
    const unsigned cntB = pB7 + ph7;
    // mbcnt64(Bj) for h=1 lanes includes all lo bits -> pre-subtract them
    const unsigned qB0 = pB0 - pl0, qB1 = pB1 - pl1, qB2 = pB2 - pl2, qB3 = pB3 - pl3;
    const unsigned qB4 = pB4 - pl4, qB5 = pB5 - pl5, qB6 = pB6 - pl6, qB7 = pB7 - pl7;

    const unsigned k0 = ordkey(c0), k1 = ordkey(c1), k2 = ordkey(c2), k3 = ordkey(c3);
    const unsigned k4 = ordkey(c4), k5 = ordkey(c5), k6 = ordkey(c6), k7 = ordkey(c7);
    const int ebase = l31 * 8;
    const bool okv = h ? (cntB <= 32u) : (cntA <= 32u);

    if (cd0 && okv) *reinterpret_cast<uint64_t*>(&rowMine[2 * ((h ? qB0 : pA0) + mbcnt64(B0))]) =
        ((uint64_t)k0 << 32) | (unsigned)(255 - ebase);
    if (cd1 && okv) *reinterpret_cast<uint64_t*>(&rowMine[2 * ((h ? qB1 : pA1) + mbcnt64(B1))]) =
        ((uint64_t)k1 << 32) | (unsigned)(255 - ebase - 1);
    if (cd2 && okv) *reinterpret_cast<uint64_t*>(&rowMine[2 * ((h ? qB2 : pA2) + mbcnt64(B2))]) =
        ((uint64_t)k2 << 32) | (unsigned)(255 - ebase - 2);
    if (cd3 && okv) *reinterpret_cast<uint64_t*>(&rowMine[2 * ((h ? qB3 : pA3) + mbcnt64(B3))]) =
        ((uint64_t)k3 << 32) | (unsigned)(255 - ebase - 3);
    if (cd4 && okv) *reinterpret_cast<uint64_t*>(&rowMine[2 * ((h ? qB4 : pA4) + mbcnt64(B4))]) =
        ((uint64_t)k4 << 32) | (unsigned)(255 - ebase - 4);
    if (cd5 && okv) *reinterpret_cast<uint64_t*>(&rowMine[2 * ((h ? qB5 : pA5) + mbcnt64(B5))]) =
        ((uint64_t)k5 << 32) | (unsigned)(255 - ebase - 5);
    if (cd6 && okv) *reinterpret_cast<uint64_t*>(&rowMine[2 * ((h ? qB6 : pA6) + mbcnt64(B6))]) =
        ((uint64_t)k6 << 32) | (unsigned)(255 - ebase - 6);
    if (cd7 && okv) *reinterpret_cast<uint64_t*>(&rowMine[2 * ((h ? qB7 : pA7) + mbcnt64(B7))]) =
        ((uint64_t)k7 << 32) | (unsigned)(255 - ebase - 7);

    // exact fallback per half (unreachable in practice): 8 rounds of argmax
    unsigned cntAp = cntA, cntBp = cntB;
    if (__builtin_expect(cntA > 32u || cntB > 32u, 0)) {
        #pragma unroll 1
        for (int tgt = 0; tgt < 2; ++tgt) {
            const unsigned cT = tgt ? cntB : cntA;
            if (cT <= 32u) continue;
            const bool act = (h == tgt);
            unsigned mk0 = act ? (keep ? k0 : 0x80000000u) : 0u;
            unsigned mk1 = act ? (keep ? k1 : 0x80000000u) : 0u;
            unsigned mk2 = act ? (keep ? k2 : 0x80000000u) : 0u;
            unsigned mk3 = act ? (keep ? k3 : 0x80000000u) : 0u;
            unsigned mk4 = act ? (keep ? k4 : 0x80000000u) : 0u;
            unsigned mk5 = act ? (keep ? k5 : 0x80000000u) : 0u;
            unsigned mk6 = act ? (keep ? k6 : 0x80000000u) : 0u;
            unsigned mk7 = act ? (keep ? k7 : 0x80000000u) : 0u;
            uint32_t* rowT = tgt ? rowB : rowA;
            #pragma unroll 1
            for (int r_ = 0; r_ < 8; ++r_) {
                unsigned hm = umax_(umax_(umax_(mk0, mk1), umax_(mk2, mk3)),
                                    umax_(umax_(mk4, mk5), umax_(mk6, mk7)));
                unsigned m = hm;
                m = umax_(m, (unsigned)__shfl_xor((int)m, 1));
                m = umax_(m, (unsigned)__shfl_xor((int)m, 2));
                m = umax_(m, (unsigned)__shfl_xor((int)m, 4));
                m = umax_(m, (unsigned)__shfl_xor((int)m, 8));
                m = umax_(m, (unsigned)__shfl_xor((int)m, 16));
                const unsigned M = rlaneu(m, tgt * 32);
                const unsigned long long bl = __ballot(hm == M);
                const int wl = __ffsll(bl) - 1;
                int slot = 7;
                if (rlaneu_s(mk6, wl) == M) slot = 6;
                if (rlaneu_s(mk5, wl) == M) slot = 5;
                if (rlaneu_s(mk4, wl) == M) slot = 4;
                if (rlaneu_s(mk3, wl) == M) slot = 3;
                if (rlaneu_s(mk2, wl) == M) slot = 2;
                if (rlaneu_s(mk1, wl) == M) slot = 1;
                if (rlaneu_s(mk0, wl) == M) slot = 0;
                if (lane == 0)
                    *reinterpret_cast<uint64_t*>(&rowT[2 * r_]) =
                        ((uint64_t)M << 32) | (unsigned)(255 - ((wl & 31) * 8 + slot));
                const bool iw = (lane == wl);
                mk0 = (iw && slot == 0) ? 0u : mk0;
                mk1 = (iw && slot == 1) ? 0u : mk1;
                mk2 = (iw && slot == 2) ? 0u : mk2;
                mk3 = (iw && slot == 3) ? 0u : mk3;
                mk4 = (iw && slot == 4) ? 0u : mk4;
                mk5 = (iw && slot == 5) ? 0u : mk5;
                mk6 = (iw && slot == 6) ? 0u : mk6;
                mk7 = (iw && slot == 7) ? 0u : mk7;
            }
            if (tgt) cntBp = 8u; else cntAp = 8u;
        }
    }

    // pad 4 zero-key slots (INS8 no-ops) + cnt, per half
    const unsigned cntH = h ? cntBp : cntAp;
    if (l31 < 4)
        *reinterpret_cast<uint64_t*>(&rowMine[2 * (cntH + l31)]) = 0ull;
    if (l31 == 0) rowMine[CNT_OFF] = cntH;
}

__global__ __launch_bounds__(256, 4) void route_kernel(
    const float* __restrict__ logits,
    const float* __restrict__ bias,
    float* __restrict__ out_idx_f,   // [T,8] indices stored as float
    float* __restrict__ out_w,       // [T,8] weights
    int T)
{
    __shared__ uint32_t cand[TPB * CDW];   // 19456 B
    __shared__ float    bias_s[NE];        // 1024 B

    const int lane = threadIdx.x & 63;
    const int wvi  = threadIdx.x >> 6;
    const long long tok0 = (long long)blockIdx.x * TPB;

    bias_s[threadIdx.x] = bias[threadIdx.x];   // 256 threads == NE

    // ===== phase 1: 2 tokens per wave per call, ILP-2 pairs, prefetch =====
    {
        const int l31 = lane & 31;
        const int h   = lane >> 5;
        const float4 bb0 = *reinterpret_cast<const float4*>(bias + l31 * 8);
        const float4 bb1 = *reinterpret_cast<const float4*>(bias + l31 * 8 + 4);
        const pf2 bp0 = {bb0.x, bb0.y}, bp1 = {bb0.z, bb0.w};
        const pf2 bp2 = {bb1.x, bb1.y}, bp3 = {bb1.z, bb1.w};
        // lane's token for pair p is (wvi*16 + 2p + h); data at lp + 2p*NE
        const float* lp = logits + (tok0 + wvi * 16 + h) * NE + l31 * 8;
        uint32_t* wrow = &cand[(wvi * 16) * CDW];
        // bpermute byte addr of group (l&3) of own half: lane (l&32)|((l&3)<<2)
        const int bpa1 = ((lane & 32) << 2) | ((lane & 3) << 4);

        float4 xa0 = *reinterpret_cast<const float4*>(lp);
        float4 xb0 = *reinterpret_cast<const float4*>(lp + 4);
        float4 xa1 = *reinterpret_cast<const float4*>(lp + 2 * NE);
        float4 xb1 = *reinterpret_cast<const float4*>(lp + 2 * NE + 4);
        float4 na0, nb0, na1, nb1;
        for (int j = 0; j < 4; ++j) {
            if (j < 3) {   // prefetch next iteration's two pairs
                na0 = *reinterpret_cast<const float4*>(lp + (4 * j + 4) * NE);
                nb0 = *reinterpret_cast<const float4*>(lp + (4 * j + 4) * NE + 4);
                na1 = *reinterpret_cast<const float4*>(lp + (4 * j + 6) * NE);
                nb1 = *reinterpret_cast<const float4*>(lp + (4 * j + 6) * NE + 4);
            }
            uint32_t* rA0 = wrow + (4 * j) * CDW;       // pair 2j:   tokens 4j,4j+1
            uint32_t* rA1 = wrow + (4 * j + 2) * CDW;   // pair 2j+1: tokens 4j+2,4j+3
            score_pair(xa0, xb0, bp0, bp1, bp2, bp3, lane, bpa1,
                       rA0, rA0 + CDW, rA0 + h * CDW);
            score_pair(xa1, xb1, bp0, bp1, bp2, bp3, lane, bpa1,
                       rA1, rA1 + CDW, rA1 + h * CDW);
            xa0 = na0; xb0 = nb0; xa1 = na1; xb1 = nb1;
        }
    }
    __syncthreads();

    // ========== phase 2: thread-per-token batched top-8 + output ==========
    if (threadIdx.x < TPB) {
        uint32_t* row = &cand[threadIdx.x * CDW];
        const long long t = tok0 + threadIdx.x;
        const unsigned cnt = row[CNT_OFF];
        const unsigned iters = (cnt + 3) >> 2;

        uint64_t v0 = 0, v1 = 0, v2 = 0, v3 = 0, v4 = 0, v5 = 0, v6 = 0, v7 = 0;
        const ulonglong2* rp = reinterpret_cast<const ulonglong2*>(row);
        for (unsigned it = 0; it < iters; ++it) {
            const ulonglong2 a = rp[2 * it];
            const ulonglong2 b = rp[2 * it + 1];
            INS8(a.x); INS8(a.y); INS8(b.x); INS8(b.y);
        }

        const int e0 = 255 - (int)(v0 & 255u);
        const int e1 = 255 - (int)(v1 & 255u);
        const int e2 = 255 - (int)(v2 & 255u);
        const int e3 = 255 - (int)(v3 & 255u);
        const int e4 = 255 - (int)(v4 & 255u);
        const int e5 = 255 - (int)(v5 & 255u);
        const int e6 = 255 - (int)(v6 & 255u);
        const int e7 = 255 - (int)(v7 & 255u);
        const float s0 = inv_ordkey((unsigned)(v0 >> 32)) - bias_s[e0];
        const float s1 = inv_ordkey((unsigned)(v1 >> 32)) - bias_s[e1];
        const float s2 = inv_ordkey((unsigned)(v2 >> 32)) - bias_s[e2];
        const float s3 = inv_ordkey((unsigned)(v3 >> 32)) - bias_s[e3];
        const float s4 = inv_ordkey((unsigned)(v4 >> 32)) - bias_s[e4];
        const float s5 = inv_ordkey((unsigned)(v5 >> 32)) - bias_s[e5];
        const float s6 = inv_ordkey((unsigned)(v6 >> 32)) - bias_s[e6];
        const float s7 = inv_ordkey((unsigned)(v7 >> 32)) - bias_s[e7];

        const float denom = ((s0 + s1) + (s2 + s3)) + ((s4 + s5) + (s6 + s7));
        const float scale = 2.5f * __builtin_amdgcn_rcpf(denom + 1e-20f);

        float4* oi = reinterpret_cast<float4*>(out_idx_f + t * TK);
        float4* ow = reinterpret_cast<float4*>(out_w + t * TK);
        oi[0] = make_float4((float)e0, (float)e1, (float)e2, (float)e3);
        oi[1] = make_float4((float)e4, (float)e5, (float)e6, (float)e7);
        ow[0] = make_float4(s0 * scale, s1 * scale, s2 * scale, s3 * scale);
        ow[1] = make_float4(s4 * scale, s5 * scale, s6 * scale, s7 * scale);
    }
}

extern "C" void kernel_launch(void* const* d_in, const int* in_sizes, int n_in,
                              void* d_out, int out_size, void* d_ws, size_t ws_size,
                              hipStream_t stream) {
    const float* logits = (const float*)d_in[0];
    const float* bias   = (const float*)d_in[1];
    const int T = in_sizes[0] / NE;

    float* out_idx_f = (float*)d_out;
    float* out_w     = (float*)d_out + (size_t)T * TK;

    const int grid = T / TPB;   // 262144 / 64 = 4096
    route_kernel<<<grid, 256, 0, stream>>>(logits, bias, out_idx_f, out_w, T);
}

// Round 18
// 88.963 us; speedup vs baseline: 1.0836x; 1.0836x over previous
//
#include <hip/hip_runtime.h>
#include <stdint.h>

#define NE 256      // experts
#define TKG 4       // top-k groups
#define TK 8        // top-k experts
#define TPB 64      // tokens per block (256 threads = 4 waves; 16 tokens/wave)
#define CDW 76      // dwords per token row: 36 u64 slots (32 cand + 4 pad) + cnt; 304B, 16B-aligned
#define CNT_OFF 72

typedef float pf2 __attribute__((ext_vector_type(2)));

// ---------- packed f32 VOP3P helpers (bit-identical IEEE, half the issues) ----------
__device__ __forceinline__ pf2 pk_fma_ss(pf2 a, pf2 b, pf2 cs) {
    pf2 d; asm("v_pk_fma_f32 %0, %1, %2, %3" : "=v"(d) : "v"(a), "v"(b), "s"(cs)); return d;
}
__device__ __forceinline__ pf2 pk_fma_sv(pf2 as, pf2 b, pf2 c) {
    pf2 d; asm("v_pk_fma_f32 %0, %1, %2, %3" : "=v"(d) : "s"(as), "v"(b), "v"(c)); return d;
}
__device__ __forceinline__ pf2 pk_fma_vv(pf2 a, pf2 b, pf2 c) {
    pf2 d; asm("v_pk_fma_f32 %0, %1, %2, %3" : "=v"(d) : "v"(a), "v"(b), "v"(c)); return d;
}
__device__ __forceinline__ pf2 pk_mul_s(pf2 a, pf2 bs) {
    pf2 d; asm("v_pk_mul_f32 %0, %1, %2" : "=v"(d) : "v"(a), "s"(bs)); return d;
}
__device__ __forceinline__ pf2 pk_mul_v(pf2 a, pf2 b) {
    pf2 d; asm("v_pk_mul_f32 %0, %1, %2" : "=v"(d) : "v"(a), "v"(b)); return d;
}
__device__ __forceinline__ pf2 pk_add_s(pf2 a, pf2 bs) {
    pf2 d; asm("v_pk_add_f32 %0, %1, %2" : "=v"(d) : "v"(a), "s"(bs)); return d;
}

// Bit-exact packed replica of numpy's SIMD float32 exp (Cephes FMA path).
// DO NOT TOUCH — validated bit-exact vs the np reference (rounds 3-16).
__device__ __forceinline__ pf2 np_expf2(pf2 v) {
    const pf2 LOG2E  = {1.44269504088896341f, 1.44269504088896341f};
    const pf2 NLN2HI = {-0.693359375f, -0.693359375f};
    const pf2 LN2LO  = {2.12194440e-4f, 2.12194440e-4f};
    const pf2 A0     = {1.9875691500E-4f, 1.9875691500E-4f};
    const pf2 A1     = {1.3981999507E-3f, 1.3981999507E-3f};
    const pf2 A2     = {8.3334519073E-3f, 8.3334519073E-3f};
    const pf2 A3     = {4.1665795894E-2f, 4.1665795894E-2f};
    const pf2 A4     = {1.6666665459E-1f, 1.6666665459E-1f};
    const pf2 A5     = {5.0000001201E-1f, 5.0000001201E-1f};
    const pf2 ONE    = {1.0f, 1.0f};

    pf2 m = pk_mul_s(v, LOG2E);
    pf2 q; q.x = rintf(m.x); q.y = rintf(m.y);
    pf2 t = pk_fma_sv(NLN2HI, q, v);
    t = pk_fma_sv(LN2LO, q, t);
    pf2 t2 = pk_mul_v(t, t);
    pf2 p = pk_fma_sv(A0, t, A1);
    p = pk_fma_ss(p, t, A2);
    p = pk_fma_ss(p, t, A3);
    p = pk_fma_ss(p, t, A4);
    p = pk_fma_ss(p, t, A5);
    p = pk_fma_vv(p, t2, t);
    p = pk_add_s(p, ONE);
    pf2 r;
    r.x = ldexpf(p.x, (int)q.x);
    r.y = ldexpf(p.y, (int)q.y);
    return r;
}

// Correctly-rounded 1/d for d in [1, 2^20] (validated r10-r16).
__device__ __forceinline__ float crdiv1(float d) {
    float y0 = __builtin_amdgcn_rcpf(d);
    float e0 = fmaf(-d, y0, 1.0f);
    float y1 = fmaf(e0, y0, y0);
    float e1 = fmaf(-d, y1, 1.0f);
    float y2 = fmaf(e1, y1, y1);
    float r  = fmaf(-d, y2, 1.0f);
    return fmaf(r, y2, y2);
}

// f32 -> monotone u32 (order-preserving). 0.0f -> 0x80000000.
__device__ __forceinline__ unsigned ordkey(float v) {
    int b = __float_as_int(v);
    return (unsigned)(b ^ ((b >> 31) | 0x80000000));
}
__device__ __forceinline__ float inv_ordkey(unsigned u) {
    unsigned b = (u & 0x80000000u) ? (u ^ 0x80000000u) : ~u;
    return __uint_as_float(b);
}

__device__ __forceinline__ float rlanef(float v, int l) {
    return __int_as_float(__builtin_amdgcn_readlane(__float_as_int(v), l));
}
__device__ __forceinline__ unsigned rlaneu(unsigned v, int l) {
    return (unsigned)__builtin_amdgcn_readlane((int)v, l);
}
__device__ __forceinline__ unsigned umax_(unsigned a, unsigned b) { return a > b ? a : b; }
__device__ __forceinline__ int mbcnt64(unsigned long long m) {
    return __builtin_amdgcn_mbcnt_hi((unsigned)(m >> 32),
           __builtin_amdgcn_mbcnt_lo((unsigned)m, 0u));
}

// DPP cross-lane read (pure VALU, no LDS).
template <int CTRL>
__device__ __forceinline__ float dppf(float x) {
    int xi = __float_as_int(x);
    return __int_as_float(__builtin_amdgcn_update_dpp(xi, xi, CTRL, 0xF, 0xF, false));
}
#define DPP_XOR1  0xB1   // quad_perm [1,0,3,2]
#define DPP_XOR2  0x4E   // quad_perm [2,3,0,1]
#define DPP_HMIRR 0x141  // row_half_mirror: l <-> l^7 within each 8
#define DPP_ROR8  0x128  // row_ror:8
#define DPP_BC15  0x142  // row_bcast15
#define DPP_BC31  0x143  // row_bcast31

// Branchless sorted-descending top-8 insertion (u64 = key<<32 | invidx).
// Zero candidates are exact no-ops.
#define INS8(cand) do {                                                \
    const uint64_t c_ = (cand);                                        \
    const bool q0 = c_ > v0, q1 = c_ > v1, q2 = c_ > v2, q3 = c_ > v3; \
    const bool q4 = c_ > v4, q5 = c_ > v5, q6 = c_ > v6, q7 = c_ > v7; \
    v7 = q7 ? (q6 ? v6 : c_) : v7;                                     \
    v6 = q6 ? (q5 ? v5 : c_) : v6;                                     \
    v5 = q5 ? (q4 ? v4 : c_) : v5;                                     \
    v4 = q4 ? (q3 ? v3 : c_) : v4;                                     \
    v3 = q3 ? (q2 ? v2 : c_) : v3;                                     \
    v2 = q2 ? (q1 ? v1 : c_) : v2;                                     \
    v1 = q1 ? (q0 ? v0 : c_) : v1;                                     \
    v0 = q0 ? c_ : v0;                                                 \
} while (0)

// Full per-token phase-1 — byte-identical logic to r14/r15/r16.
__device__ __forceinline__ void score_token(
    const float4 cur, const pf2 biasL, const pf2 biasH,
    const int lane, const int bpa, uint32_t* row)
{
    const pf2 ONE = {1.0f, 1.0f};
    pf2 eA = np_expf2((pf2){-cur.x, -cur.y});
    pf2 eB = np_expf2((pf2){-cur.z, -cur.w});
    pf2 dA = pk_add_s(eA, ONE);
    pf2 dB = pk_add_s(eB, ONE);
    const float s0 = crdiv1(dA.x);
    const float s1 = crdiv1(dA.y);
    const float s2 = crdiv1(dB.x);
    const float s3 = crdiv1(dB.y);
    const float c0 = s0 + biasL.x;
    const float c1 = s1 + biasL.y;
    const float c2 = s2 + biasH.x;
    const float c3 = s3 + biasH.y;

    // local sorted top-2 of my 4 values
    float a1 = fmaxf(c0, c1), a2 = fminf(c0, c1);
    float d1 = fmaxf(c2, c3), d2 = fminf(c2, c3);
    float m1 = fmaxf(a1, d1);
    float m2 = fmaxf(fminf(a1, d1), fmaxf(a2, d2));

    // DPP butterfly within the 8-lane group (top-2 values tree-invariant)
    {
        float p1 = dppf<DPP_XOR1>(m1), p2 = dppf<DPP_XOR1>(m2);
        float n1 = fmaxf(m1, p1);
        m2 = fmaxf(fminf(m1, p1), fmaxf(m2, p2)); m1 = n1;
    }
    {
        float p1 = dppf<DPP_XOR2>(m1), p2 = dppf<DPP_XOR2>(m2);
        float n1 = fmaxf(m1, p1);
        m2 = fmaxf(fminf(m1, p1), fmaxf(m2, p2)); m1 = n1;
    }
    {
        float p1 = dppf<DPP_HMIRR>(m1), p2 = dppf<DPP_HMIRR>(m2);
        float n1 = fmaxf(m1, p1);
        m2 = fmaxf(fminf(m1, p1), fmaxf(m2, p2)); m1 = n1;
    }
    const float gs = m1 + m2;   // group-uniform

    // transpose-rank (one bpermute + 2 ballots + SALU byte popcounts)
    const float gb = __int_as_float(
        __builtin_amdgcn_ds_bpermute(bpa, __float_as_int(gs)));
    const unsigned long long gtm = __ballot(gb > gs);
    const unsigned long long eqm = __ballot(gb == gs);
    const unsigned long long term = gtm | (eqm & 0x7F3F1F0F07030100ull);
    unsigned km8 = 0;
    #pragma unroll
    for (int a = 0; a < 8; ++a)
        km8 |= (unsigned)(__popcll((term >> (8 * a)) & 0xFFull) < 4 ? 1u : 0u) << a;
    const int g = lane >> 3;
    const bool keep = (km8 >> g) & 1u;

    // tau0 = min over kept groups of m2 (DPP min-reduce; result at lane 63)
    const float inf_ = __uint_as_float(0x7F800000u);
    float mm = keep ? m2 : inf_;
    mm = fminf(mm, dppf<DPP_ROR8>(mm));
    mm = fminf(mm, dppf<DPP_BC15>(mm));
    mm = fminf(mm, dppf<DPP_BC31>(mm));
    const float t0f = rlanef(mm, 63);

    // candidate filter + ballot compaction (exec-masked stores)
    const bool cd0 = keep && (c0 >= t0f);
    const bool cd1 = keep && (c1 >= t0f);
    const bool cd2 = keep && (c2 >= t0f);
    const bool cd3 = keep && (c3 >= t0f);
    const unsigned long long b0 = __ballot(cd0);
    const unsigned long long b1 = __ballot(cd1);
    const unsigned long long b2 = __ballot(cd2);
    const unsigned long long b3 = __ballot(cd3);
    const unsigned p1_ = __popcll(b0);
    const unsigned p2_ = p1_ + __popcll(b1);
    const unsigned p3_ = p2_ + __popcll(b2);
    unsigned cnt = p3_ + __popcll(b3);

    const unsigned k0 = ordkey(c0);
    const unsigned k1 = ordkey(c1);
    const unsigned k2 = ordkey(c2);
    const unsigned k3 = ordkey(c3);

    const int base = lane * 4;
    if (cnt <= 32u) {
        if (cd0) *reinterpret_cast<uint64_t*>(&row[2 * (0u  + mbcnt64(b0))]) =
            ((uint64_t)k0 << 32) | (unsigned)(255 - base);
        if (cd1) *reinterpret_cast<uint64_t*>(&row[2 * (p1_ + mbcnt64(b1))]) =
            ((uint64_t)k1 << 32) | (unsigned)(255 - base - 1);
        if (cd2) *reinterpret_cast<uint64_t*>(&row[2 * (p2_ + mbcnt64(b2))]) =
            ((uint64_t)k2 << 32) | (unsigned)(255 - base - 2);
        if (cd3) *reinterpret_cast<uint64_t*>(&row[2 * (p3_ + mbcnt64(b3))]) =
            ((uint64_t)k3 << 32) | (unsigned)(255 - base - 3);
    } else {
        // exact fallback (unreachable in practice): 8 rounds of wave argmax
        unsigned mk0 = keep ? k0 : 0x80000000u;
        unsigned mk1 = keep ? k1 : 0x80000000u;
        unsigned mk2 = keep ? k2 : 0x80000000u;
        unsigned mk3 = keep ? k3 : 0x80000000u;
        for (int r = 0; r < TK; ++r) {
            unsigned h = umax_(umax_(mk0, mk1), umax_(mk2, mk3));
            unsigned m = h;
            m = umax_(m, (unsigned)__shfl_xor((int)m, 1));
            m = umax_(m, (unsigned)__shfl_xor((int)m, 2));
            m = umax_(m, (unsigned)__shfl_xor((int)m, 4));
            m = umax_(m, (unsigned)__shfl_xor((int)m, 8));
            const unsigned M = umax_(umax_(rlaneu(m, 0), rlaneu(m, 16)),
                                     umax_(rlaneu(m, 32), rlaneu(m, 48)));
            const unsigned long long bl = __ballot(h == M);
            const int wl = __ffsll(bl) - 1;
            const unsigned long long sb0 = __ballot(mk0 == M);
            const unsigned long long sb1 = __ballot(mk1 == M);
            const unsigned long long sb2 = __ballot(mk2 == M);
            const int slot = ((sb0 >> wl) & 1) ? 0 : ((sb1 >> wl) & 1) ? 1
                           : ((sb2 >> wl) & 1) ? 2 : 3;
            if (lane == r)
                *reinterpret_cast<uint64_t*>(&row[2 * r]) =
                    ((uint64_t)M << 32) | (unsigned)(255 - (wl * 4 + slot));
            const bool iw = (lane == wl);
            mk0 = (iw && slot == 0) ? 0u : mk0;
            mk1 = (iw && slot == 1) ? 0u : mk1;
            mk2 = (iw && slot == 2) ? 0u : mk2;
            mk3 = (iw && slot == 3) ? 0u : mk3;
        }
        cnt = 8;
    }
    // pad slots cnt..cnt+3 with zero keys (INS8 no-ops) for batched phase-2
    if (lane < 4)
        *reinterpret_cast<uint64_t*>(&row[2 * (cnt + lane)]) = 0ull;
    if (lane == 0) row[CNT_OFF] = cnt;
}

__global__ __launch_bounds__(256, 4) void route_kernel(
    const float* __restrict__ logits,
    const float* __restrict__ bias,
    float* __restrict__ out_idx_f,   // [T,8] indices stored as float
    float* __restrict__ out_w,       // [T,8] weights
    int T)
{
    __shared__ uint32_t cand[TPB * CDW];   // 19456 B (16B-aligned rows)
    __shared__ float    bias_s[NE];        // 1024 B

    const int lane = threadIdx.x & 63;
    const int wvi  = threadIdx.x >> 6;
    const long long tok0 = (long long)blockIdx.x * TPB;

    bias_s[threadIdx.x] = bias[threadIdx.x];   // 256 threads == NE

    // ===== phase 1: wave-per-token scoring, 2-token ILP, 2-deep prefetch =====
    {
        const float4 bias4 = *reinterpret_cast<const float4*>(bias + lane * 4);
        const pf2 biasL = {bias4.x, bias4.y};
        const pf2 biasH = {bias4.z, bias4.w};
        const float* lp = logits + (tok0 + wvi * 16) * NE + lane * 4;
        uint32_t* wrow = &cand[(wvi * 16) * CDW];
        const int bpa = (lane & 7) << 5;   // bpermute byte-addr: lane (lane&7)*8

        float4 cA = *reinterpret_cast<const float4*>(lp);            // pair 0
        float4 cB = *reinterpret_cast<const float4*>(lp + NE);
        float4 dA = *reinterpret_cast<const float4*>(lp + 2 * NE);   // pair 1
        float4 dB = *reinterpret_cast<const float4*>(lp + 3 * NE);
        float4 eA, eB;
        for (int i = 0; i < 8; ++i) {
            if (i < 6) {   // issue loads for pair i+2
                eA = *reinterpret_cast<const float4*>(lp + (2 * i + 4) * NE);
                eB = *reinterpret_cast<const float4*>(lp + (2 * i + 5) * NE);
            }
            score_token(cA, biasL, biasH, lane, bpa, wrow + (2 * i) * CDW);
            score_token(cB, biasL, biasH, lane, bpa, wrow + (2 * i + 1) * CDW);
            cA = dA; cB = dB; dA = eA; dB = eB;
        }
    }
    __syncthreads();

    // ========== phase 2: thread-per-token batched top-8 + output ==========
    if (threadIdx.x < TPB) {
        uint32_t* row = &cand[threadIdx.x * CDW];
        const long long t = tok0 + threadIdx.x;
        const unsigned cnt = row[CNT_OFF];
        const unsigned iters = (cnt + 3) >> 2;

        uint64_t v0 = 0, v1 = 0, v2 = 0, v3 = 0, v4 = 0, v5 = 0, v6 = 0, v7 = 0;
        const ulonglong2* rp = reinterpret_cast<const ulonglong2*>(row);
        for (unsigned it = 0; it < iters; ++it) {
            const ulonglong2 a = rp[2 * it];       // ds_read_b128
            const ulonglong2 b = rp[2 * it + 1];   // ds_read_b128
            INS8(a.x); INS8(a.y); INS8(b.x); INS8(b.y);
        }

        const int e0 = 255 - (int)(v0 & 255u);
        const int e1 = 255 - (int)(v1 & 255u);
        const int e2 = 255 - (int)(v2 & 255u);
        const int e3 = 255 - (int)(v3 & 255u);
        const int e4 = 255 - (int)(v4 & 255u);
        const int e5 = 255 - (int)(v5 & 255u);
        const int e6 = 255 - (int)(v6 & 255u);
        const int e7 = 255 - (int)(v7 & 255u);
        const float s0 = inv_ordkey((unsigned)(v0 >> 32)) - bias_s[e0];
        const float s1 = inv_ordkey((unsigned)(v1 >> 32)) - bias_s[e1];
        const float s2 = inv_ordkey((unsigned)(v2 >> 32)) - bias_s[e2];
        const float s3 = inv_ordkey((unsigned)(v3 >> 32)) - bias_s[e3];
        const float s4 = inv_ordkey((unsigned)(v4 >> 32)) - bias_s[e4];
        const float s5 = inv_ordkey((unsigned)(v5 >> 32)) - bias_s[e5];
        const float s6 = inv_ordkey((unsigned)(v6 >> 32)) - bias_s[e6];
        const float s7 = inv_ordkey((unsigned)(v7 >> 32)) - bias_s[e7];

        const float denom = ((s0 + s1) + (s2 + s3)) + ((s4 + s5) + (s6 + s7));
        const float scale = 2.5f * __builtin_amdgcn_rcpf(denom + 1e-20f);

        float4* oi = reinterpret_cast<float4*>(out_idx_f + t * TK);
        float4* ow = reinterpret_cast<float4*>(out_w + t * TK);
        oi[0] = make_float4((float)e0, (float)e1, (float)e2, (float)e3);
        oi[1] = make_float4((float)e4, (float)e5, (float)e6, (float)e7);
        ow[0] = make_float4(s0 * scale, s1 * scale, s2 * scale, s3 * scale);
        ow[1] = make_float4(s4 * scale, s5 * scale, s6 * scale, s7 * scale);
    }
}

extern "C" void kernel_launch(void* const* d_in, const int* in_sizes, int n_in,
                              void* d_out, int out_size, void* d_ws, size_t ws_size,
                              hipStream_t stream) {
    const float* logits = (const float*)d_in[0];
    const float* bias   = (const float*)d_in[1];
    const int T = in_sizes[0] / NE;

    float* out_idx_f = (float*)d_out;
    float* out_w     = (float*)d_out + (size_t)T * TK;

    const int grid = T / TPB;   // 262144 / 64 = 4096
    route_kernel<<<grid, 256, 0, stream>>>(logits, bias, out_idx_f, out_w, T);
}